// Round 9
// baseline (623.527 us; speedup 1.0000x reference)
//
#include <hip/hip_runtime.h>
#include <math.h>

#define NB 256   // graphs
#define NP 512   // points per graph
#define NH 16    // hidden dim
#define NK 8     // neighbors

__device__ __forceinline__ float elu_f(float x) { return x > 0.0f ? x : expm1f(x); }

__global__ __launch_bounds__(256) void k_encoder(
    const float* __restrict__ x,
    const float* __restrict__ We1, const float* __restrict__ be1,
    const float* __restrict__ We2, const float* __restrict__ be2,
    float* __restrict__ h, float* __restrict__ sq)
{
    int i = blockIdx.x * 256 + threadIdx.x;           // 0 .. NB*NP-1
    float4 xv = reinterpret_cast<const float4*>(x)[i];
    float h1[NH];
#pragma unroll
    for (int o = 0; o < NH; ++o) {
        float a = be1[o];
        a = fmaf(xv.x, We1[0*NH+o], a);
        a = fmaf(xv.y, We1[1*NH+o], a);
        a = fmaf(xv.z, We1[2*NH+o], a);
        a = fmaf(xv.w, We1[3*NH+o], a);
        h1[o] = elu_f(a);
    }
    float hv[NH];
    float s = 0.0f;
#pragma unroll
    for (int o = 0; o < NH; ++o) {
        float a = be2[o];
#pragma unroll
        for (int q = 0; q < NH; ++q) a = fmaf(h1[q], We2[q*NH+o], a);
        a = elu_f(a);
        hv[o] = a;
        s = fmaf(a, a, s);
    }
#pragma unroll
    for (int d = 0; d < NH; d += 4)
        *reinterpret_cast<float4*>(h + (size_t)i*NH + d) =
            make_float4(hv[d], hv[d+1], hv[d+2], hv[d+3]);
    sq[i] = s;
}

// One block per graph; thread t owns point t. Neighbor rows are read with
// wave-uniform addresses -> scalar (s_load) path, keeping the VALU free for FMAs.
template<int FINAL>
__global__ __launch_bounds__(512) void k_conv(
    const float* __restrict__ hin, const float* __restrict__ sqin,
    const float* __restrict__ Wc, const float* __restrict__ bc,
    float* hout, float* sqout,
    const float* __restrict__ Wo1, const float* __restrict__ bo1,
    const float* __restrict__ Wo2, const float* __restrict__ bo2,
    const float* __restrict__ Wo3, const float* __restrict__ bo3,
    float* __restrict__ out)
{
    const int g = blockIdx.x;
    const int t = threadIdx.x;
    const int i = g * NP + t;
    const float* hg  = hin  + (size_t)g * NP * NH;
    const float* sqg = sqin + (size_t)g * NP;

    float xi[NH];
#pragma unroll
    for (int d = 0; d < NH; d += 4) {
        float4 v = *reinterpret_cast<const float4*>(hin + (size_t)i*NH + d);
        xi[d]=v.x; xi[d+1]=v.y; xi[d+2]=v.z; xi[d+3]=v.w;
    }
    const float sqi = sqg[t];

    // top-8 smallest d2, stable ties (earlier index wins) == jax.lax.top_k(-d2, 8)
    float bd[NK]; int bj[NK];
#pragma unroll
    for (int k = 0; k < NK; ++k) { bd[k] = 3.402823466e38f; bj[k] = 0; }

#pragma unroll 4
    for (int j = 0; j < NP; ++j) {
        const float* row = hg + j*NH;       // uniform across wave -> s_load
        float dot = 0.0f;
#pragma unroll
        for (int d = 0; d < NH; ++d) dot = fmaf(row[d], xi[d], dot);
        float d2 = sqi + sqg[j] - 2.0f*dot;
        if (d2 < bd[NK-1]) {
            float dc = d2; int jc = j;
#pragma unroll
            for (int k = 0; k < NK; ++k) {
                if (dc < bd[k]) {
                    float td = bd[k]; int tj = bj[k];
                    bd[k] = dc; bj[k] = jc; dc = td; jc = tj;
                }
            }
        }
    }

    // edge MLP: m = elu([xi, xj-xi] @ Wc + bc); xi-part is shared by all 8 edges
    float base[NH];
#pragma unroll
    for (int o = 0; o < NH; ++o) base[o] = bc[o];
#pragma unroll
    for (int d = 0; d < NH; ++d) {
        float xv = xi[d];
#pragma unroll
        for (int o = 0; o < NH; ++o) base[o] = fmaf(xv, Wc[d*NH+o], base[o]);
    }

    float f[NH];
#pragma unroll
    for (int o = 0; o < NH; ++o) f[o] = -3.402823466e38f;
#pragma unroll
    for (int k = 0; k < NK; ++k) {
        const float* rj = hg + (size_t)bj[k]*NH;   // per-lane address -> vector load (L2-hot)
        float m[NH];
#pragma unroll
        for (int o = 0; o < NH; ++o) m[o] = base[o];
#pragma unroll
        for (int d = 0; d < NH; ++d) {
            float dx = rj[d] - xi[d];
#pragma unroll
            for (int o = 0; o < NH; ++o) m[o] = fmaf(dx, Wc[(NH+d)*NH+o], m[o]);
        }
#pragma unroll
        for (int o = 0; o < NH; ++o) f[o] = fmaxf(f[o], elu_f(m[o]));
    }

    if (FINAL == 0) {
        __syncthreads();   // all reads of hin done block-wide -> safe even if hout aliases hin
        float s = 0.0f;
#pragma unroll
        for (int d = 0; d < NH; ++d) s = fmaf(f[d], f[d], s);
#pragma unroll
        for (int d = 0; d < NH; d += 4)
            *reinterpret_cast<float4*>(hout + (size_t)i*NH + d) =
                make_float4(f[d], f[d+1], f[d+2], f[d+3]);
        sqout[i] = s;
    } else {
        __shared__ float red[8][NH];
#pragma unroll
        for (int d = 0; d < NH; ++d) {
            float v = f[d];
            v += __shfl_down(v, 32);
            v += __shfl_down(v, 16);
            v += __shfl_down(v, 8);
            v += __shfl_down(v, 4);
            v += __shfl_down(v, 2);
            v += __shfl_down(v, 1);
            f[d] = v;
        }
        const int lane = t & 63, w = t >> 6;
        if (lane == 0) {
#pragma unroll
            for (int d = 0; d < NH; ++d) red[w][d] = f[d];
        }
        __syncthreads();
        if (t == 0) {
            float pooled[NH];
#pragma unroll
            for (int d = 0; d < NH; ++d) {
                float s = red[0][d];
#pragma unroll
                for (int w2 = 1; w2 < 8; ++w2) s += red[w2][d];
                pooled[d] = s * (1.0f/512.0f);
            }
            float o1[8];
#pragma unroll
            for (int o = 0; o < 8; ++o) {
                float a = bo1[o];
#pragma unroll
                for (int q = 0; q < NH; ++q) a = fmaf(pooled[q], Wo1[q*8+o], a);
                o1[o] = elu_f(a);
            }
            float o2[4];
#pragma unroll
            for (int o = 0; o < 4; ++o) {
                float a = bo2[o];
#pragma unroll
                for (int q = 0; q < 8; ++q) a = fmaf(o1[q], Wo2[q*4+o], a);
                o2[o] = elu_f(a);
            }
            float r = bo3[0];
#pragma unroll
            for (int q = 0; q < 4; ++q) r = fmaf(o2[q], Wo3[q], r);
            out[g] = r;                 // output 0: (256,1) float32
            out[NB + g] = (float)g;     // output 1: arange(256) written as float
        }
    }
}

extern "C" void kernel_launch(void* const* d_in, const int* in_sizes, int n_in,
                              void* d_out, int out_size, void* d_ws, size_t ws_size,
                              hipStream_t stream)
{
    const float* x   = (const float*)d_in[0];
    const float* We1 = (const float*)d_in[3];
    const float* be1 = (const float*)d_in[4];
    const float* We2 = (const float*)d_in[5];
    const float* be2 = (const float*)d_in[6];
    const float* Wc  = (const float*)d_in[7];
    const float* bc  = (const float*)d_in[8];
    const float* Wo1 = (const float*)d_in[9];
    const float* bo1 = (const float*)d_in[10];
    const float* Wo2 = (const float*)d_in[11];
    const float* bo2 = (const float*)d_in[12];
    const float* Wo3 = (const float*)d_in[13];
    const float* bo3 = (const float*)d_in[14];
    float* out = (float*)d_out;

    const size_t NPTS = (size_t)NB * NP;
    float* h   = (float*)d_ws;            // NPTS*NH
    float* sq0 = h + NPTS*NH;             // NPTS
    float* f1;
    float* sq1;
    const size_t need = (NPTS*NH + NPTS) * 2 * sizeof(float);
    if (ws_size >= need) {
        f1  = sq0 + NPTS;
        sq1 = f1 + NPTS*NH;
    } else {                               // in-place fallback (barrier-protected)
        f1  = h;
        sq1 = sq0;
    }

    k_encoder<<<dim3((unsigned)(NPTS/256)), dim3(256), 0, stream>>>(
        x, We1, be1, We2, be2, h, sq0);
    k_conv<0><<<dim3(NB), dim3(512), 0, stream>>>(
        h, sq0, Wc, bc, f1, sq1,
        nullptr, nullptr, nullptr, nullptr, nullptr, nullptr, nullptr);
    k_conv<1><<<dim3(NB), dim3(512), 0, stream>>>(
        f1, sq1, Wc, bc, nullptr, nullptr,
        Wo1, bo1, Wo2, bo2, Wo3, bo3, out);
}

// Round 11
// 607.342 us; speedup vs baseline: 1.0266x; 1.0266x over previous
//
#include <hip/hip_runtime.h>
#include <math.h>

#define NB 256   // graphs
#define NP 512   // points per graph
#define NH 16    // hidden dim
#define NK 8     // neighbors

__device__ __forceinline__ float elu_f(float x) { return x > 0.0f ? x : expm1f(x); }

__global__ __launch_bounds__(256) void k_encoder(
    const float* __restrict__ x,
    const float* __restrict__ We1, const float* __restrict__ be1,
    const float* __restrict__ We2, const float* __restrict__ be2,
    float* __restrict__ h, float* __restrict__ sq)
{
    int i = blockIdx.x * 256 + threadIdx.x;           // 0 .. NB*NP-1
    float4 xv = reinterpret_cast<const float4*>(x)[i];
    float h1[NH];
#pragma unroll
    for (int o = 0; o < NH; ++o) {
        float a = be1[o];
        a = fmaf(xv.x, We1[0*NH+o], a);
        a = fmaf(xv.y, We1[1*NH+o], a);
        a = fmaf(xv.z, We1[2*NH+o], a);
        a = fmaf(xv.w, We1[3*NH+o], a);
        h1[o] = elu_f(a);
    }
    float hv[NH];
    float s = 0.0f;
#pragma unroll
    for (int o = 0; o < NH; ++o) {
        float a = be2[o];
#pragma unroll
        for (int q = 0; q < NH; ++q) a = fmaf(h1[q], We2[q*NH+o], a);
        a = elu_f(a);
        hv[o] = a;
        s = fmaf(a, a, s);
    }
#pragma unroll
    for (int d = 0; d < NH; d += 4)
        *reinterpret_cast<float4*>(h + (size_t)i*NH + d) =
            make_float4(hv[d], hv[d+1], hv[d+2], hv[d+3]);
    sq[i] = s;
}

// One block per graph; thread t owns point t. The graph's h-tile (32KB) and
// sq (2KB) are staged in LDS once; the 512-iteration scan then reads rows at a
// wave-UNIFORM LDS address (broadcast, conflict-free, ~1 VALU addr op per j)
// instead of per-lane flat global loads (the round-9 counter analysis showed
// ~280 VALU instrs/j, ~190 of them unexplained by math -> load path suspect).
template<int FINAL>
__global__ __launch_bounds__(512) void k_conv(
    const float* __restrict__ hin, const float* __restrict__ sqin,
    const float* __restrict__ Wc, const float* __restrict__ bc,
    float* hout, float* sqout,
    const float* __restrict__ Wo1, const float* __restrict__ bo1,
    const float* __restrict__ Wo2, const float* __restrict__ bo2,
    const float* __restrict__ Wo3, const float* __restrict__ bo3,
    float* __restrict__ out)
{
    __shared__ float hs[NP * NH];    // 32 KB: this graph's feature rows
    __shared__ float sqs[NP];        //  2 KB: row norms

    const int g = blockIdx.x;
    const int t = threadIdx.x;

    // ---- stage: thread t copies row t (coalesced global read, keeps own row in regs)
    float xi[NH];
    {
        const float4* hg4 = reinterpret_cast<const float4*>(hin + (size_t)g * NP * NH);
        float4* hs4 = reinterpret_cast<float4*>(hs);
#pragma unroll
        for (int d4 = 0; d4 < 4; ++d4) {
            float4 v = hg4[(size_t)t * 4 + d4];
            hs4[t * 4 + d4] = v;
            xi[d4*4+0] = v.x; xi[d4*4+1] = v.y; xi[d4*4+2] = v.z; xi[d4*4+3] = v.w;
        }
    }
    const float sqi = sqin[(size_t)g * NP + t];
    sqs[t] = sqi;
    __syncthreads();

    // ---- top-8 smallest d2, stable ties (earlier index wins) == jax.lax.top_k(-d2, 8)
    float bd[NK]; int bj[NK];
#pragma unroll
    for (int k = 0; k < NK; ++k) { bd[k] = 3.402823466e38f; bj[k] = 0; }

#pragma unroll 4
    for (int j = 0; j < NP; ++j) {
        const float* row = hs + j * NH;          // uniform LDS addr -> broadcast
        float dot = 0.0f;
#pragma unroll
        for (int d = 0; d < NH; ++d) dot = fmaf(row[d], xi[d], dot);
        float d2 = sqi + sqs[j] - 2.0f * dot;    // EXACT ref expression order
        if (d2 < bd[NK-1]) {
            float dc = d2; int jc = j;
#pragma unroll
            for (int k = 0; k < NK; ++k) {
                if (dc < bd[k]) {
                    float td = bd[k]; int tj = bj[k];
                    bd[k] = dc; bj[k] = jc; dc = td; jc = tj;
                }
            }
        }
    }

    // ---- edge MLP: m = elu([xi, xj-xi] @ Wc + bc); xi-part shared by all 8 edges
    float base[NH];
#pragma unroll
    for (int o = 0; o < NH; ++o) base[o] = bc[o];
#pragma unroll
    for (int d = 0; d < NH; ++d) {
        float xv = xi[d];
#pragma unroll
        for (int o = 0; o < NH; ++o) base[o] = fmaf(xv, Wc[d*NH+o], base[o]);
    }

    float f[NH];
#pragma unroll
    for (int o = 0; o < NH; ++o) f[o] = -3.402823466e38f;
#pragma unroll
    for (int k = 0; k < NK; ++k) {
        const float* rj = hs + bj[k] * NH;       // per-lane LDS gather (L2-free)
        float m[NH];
#pragma unroll
        for (int o = 0; o < NH; ++o) m[o] = base[o];
#pragma unroll
        for (int d = 0; d < NH; ++d) {
            float dx = rj[d] - xi[d];
#pragma unroll
            for (int o = 0; o < NH; ++o) m[o] = fmaf(dx, Wc[(NH+d)*NH+o], m[o]);
        }
#pragma unroll
        for (int o = 0; o < NH; ++o) f[o] = fmaxf(f[o], elu_f(m[o]));
    }

    if (FINAL == 0) {
        // All data for this graph came from LDS; writes touch only this graph's
        // rows, which are fully staged -> safe even if hout aliases hin.
        float s = 0.0f;
#pragma unroll
        for (int d = 0; d < NH; ++d) s = fmaf(f[d], f[d], s);
#pragma unroll
        for (int d = 0; d < NH; d += 4)
            *reinterpret_cast<float4*>(hout + (size_t)(g * NP + t) * NH + d) =
                make_float4(f[d], f[d+1], f[d+2], f[d+3]);
        sqout[(size_t)g * NP + t] = s;
    } else {
        __shared__ float red[8][NH];
#pragma unroll
        for (int d = 0; d < NH; ++d) {
            float v = f[d];
            v += __shfl_down(v, 32);
            v += __shfl_down(v, 16);
            v += __shfl_down(v, 8);
            v += __shfl_down(v, 4);
            v += __shfl_down(v, 2);
            v += __shfl_down(v, 1);
            f[d] = v;
        }
        const int lane = t & 63, w = t >> 6;
        if (lane == 0) {
#pragma unroll
            for (int d = 0; d < NH; ++d) red[w][d] = f[d];
        }
        __syncthreads();
        if (t == 0) {
            float pooled[NH];
#pragma unroll
            for (int d = 0; d < NH; ++d) {
                float s = red[0][d];
#pragma unroll
                for (int w2 = 1; w2 < 8; ++w2) s += red[w2][d];
                pooled[d] = s * (1.0f/512.0f);
            }
            float o1[8];
#pragma unroll
            for (int o = 0; o < 8; ++o) {
                float a = bo1[o];
#pragma unroll
                for (int q = 0; q < NH; ++q) a = fmaf(pooled[q], Wo1[q*8+o], a);
                o1[o] = elu_f(a);
            }
            float o2[4];
#pragma unroll
            for (int o = 0; o < 4; ++o) {
                float a = bo2[o];
#pragma unroll
                for (int q = 0; q < 8; ++q) a = fmaf(o1[q], Wo2[q*4+o], a);
                o2[o] = elu_f(a);
            }
            float r = bo3[0];
#pragma unroll
            for (int q = 0; q < 4; ++q) r = fmaf(o2[q], Wo3[q], r);
            out[g] = r;                 // output 0: (256,1) float32
            out[NB + g] = (float)g;     // output 1: arange(256) written as float
        }
    }
}

extern "C" void kernel_launch(void* const* d_in, const int* in_sizes, int n_in,
                              void* d_out, int out_size, void* d_ws, size_t ws_size,
                              hipStream_t stream)
{
    const float* x   = (const float*)d_in[0];
    const float* We1 = (const float*)d_in[3];
    const float* be1 = (const float*)d_in[4];
    const float* We2 = (const float*)d_in[5];
    const float* be2 = (const float*)d_in[6];
    const float* Wc  = (const float*)d_in[7];
    const float* bc  = (const float*)d_in[8];
    const float* Wo1 = (const float*)d_in[9];
    const float* bo1 = (const float*)d_in[10];
    const float* Wo2 = (const float*)d_in[11];
    const float* bo2 = (const float*)d_in[12];
    const float* Wo3 = (const float*)d_in[13];
    const float* bo3 = (const float*)d_in[14];
    float* out = (float*)d_out;

    const size_t NPTS = (size_t)NB * NP;
    float* h   = (float*)d_ws;            // NPTS*NH
    float* sq0 = h + NPTS*NH;             // NPTS
    float* f1;
    float* sq1;
    const size_t need = (NPTS*NH + NPTS) * 2 * sizeof(float);
    if (ws_size >= need) {
        f1  = sq0 + NPTS;
        sq1 = f1 + NPTS*NH;
    } else {                               // in-place fallback (LDS-staging-protected)
        f1  = h;
        sq1 = sq0;
    }

    k_encoder<<<dim3((unsigned)(NPTS/256)), dim3(256), 0, stream>>>(
        x, We1, be1, We2, be2, h, sq0);
    k_conv<0><<<dim3(NB), dim3(512), 0, stream>>>(
        h, sq0, Wc, bc, f1, sq1,
        nullptr, nullptr, nullptr, nullptr, nullptr, nullptr, nullptr);
    k_conv<1><<<dim3(NB), dim3(512), 0, stream>>>(
        f1, sq1, Wc, bc, nullptr, nullptr,
        Wo1, bo1, Wo2, bo2, Wo3, bo3, out);
}